// Round 3
// baseline (517.438 us; speedup 1.0000x reference)
//
#include <hip/hip_runtime.h>
#include <hip/hip_fp16.h>

// N=50000 nodes, E=850000 edges, H=8 heads, D=32, H*D=256, IN=128, SM=256, SP=128

typedef unsigned int uint32;
typedef unsigned short u16;
typedef short short8 __attribute__((ext_vector_type(8)));
typedef float f32x4 __attribute__((ext_vector_type(4)));
typedef _Float16 f16x2 __attribute__((ext_vector_type(2)));

union H2 { f16x2 v; uint32 u; };

// fp32 -> bf16 round-to-nearest-even (low 16 bits)
__device__ __forceinline__ uint32 bf_rne(uint32 u) { return (u + 0x7fffu + ((u >> 16) & 1u)) >> 16; }

// cheap split: hi = trunc-bf16(a), lo = trunc-bf16(a - hi); packed pairs via v_perm
__device__ __forceinline__ void split_trunc(float a, float b, uint32& h, uint32& l) {
  uint32 ua = __float_as_uint(a), ub = __float_as_uint(b);
  h = __builtin_amdgcn_perm(ub, ua, 0x07060302u);  // [ub.hi16 | ua.hi16]
  float ra = a - __uint_as_float(ua & 0xffff0000u);
  float rb = b - __uint_as_float(ub & 0xffff0000u);
  l = __builtin_amdgcn_perm(__float_as_uint(rb), __float_as_uint(ra), 0x07060302u);
}

__device__ __forceinline__ int wave_incl_scan(int x) {
  int lane = threadIdx.x & 63;
#pragma unroll
  for (int off = 1; off < 64; off <<= 1) {
    int t = __shfl_up(x, off, 64);
    if (lane >= off) x += t;
  }
  return x;
}

// ---------------- CSR build ----------------
__global__ __launch_bounds__(256) void k_deg(const int* __restrict__ dst, int* __restrict__ deg, int E) {
  int e = blockIdx.x * 256 + threadIdx.x;
  if (e < E) atomicAdd(&deg[dst[e]], 1);
}

__global__ __launch_bounds__(256) void k_blkscan(const int* __restrict__ in, int* __restrict__ out,
                                                 int* __restrict__ blksum, int n) {
  __shared__ int wsum[4];
  int tid = threadIdx.x;
  int i0 = blockIdx.x * 1024 + tid * 4;
  int v0 = 0, v1 = 0, v2 = 0, v3 = 0;
  if (i0 + 3 < n) {
    int4 t = *(const int4*)(in + i0);
    v0 = t.x; v1 = t.y; v2 = t.z; v3 = t.w;
  } else {
    if (i0 < n) v0 = in[i0];
    if (i0 + 1 < n) v1 = in[i0 + 1];
    if (i0 + 2 < n) v2 = in[i0 + 2];
    if (i0 + 3 < n) v3 = in[i0 + 3];
  }
  int ts = v0 + v1 + v2 + v3;
  int incl = wave_incl_scan(ts);
  int lane = tid & 63, wid = tid >> 6;
  if (lane == 63) wsum[wid] = incl;
  __syncthreads();
  if (tid == 0) {
    int a = wsum[0], b = wsum[1], c = wsum[2], d = wsum[3];
    wsum[0] = 0; wsum[1] = a; wsum[2] = a + b; wsum[3] = a + b + c;
    blksum[blockIdx.x] = a + b + c + d;
  }
  __syncthreads();
  int excl = wsum[wid] + incl - ts;
  if (i0 + 3 < n) {
    int4 o; o.x = excl; o.y = excl + v0; o.z = excl + v0 + v1; o.w = excl + v0 + v1 + v2;
    *(int4*)(out + i0) = o;
  } else {
    if (i0 < n) out[i0] = excl;
    if (i0 + 1 < n) out[i0 + 1] = excl + v0;
    if (i0 + 2 < n) out[i0 + 2] = excl + v0 + v1;
    if (i0 + 3 < n) out[i0 + 3] = excl + v0 + v1 + v2;
  }
}

__global__ void k_scan_top(int* __restrict__ bs, int G) {
  int lane = threadIdx.x;  // 64 threads
  int base = 0;
  for (int s = 0; s < G; s += 64) {
    int i = s + lane;
    int v = (i < G) ? bs[i] : 0;
    int incl = wave_incl_scan(v);
    if (i < G) bs[i] = base + incl - v;
    base += __shfl(incl, 63, 64);
  }
}

__global__ __launch_bounds__(256) void k_addoff(int* __restrict__ rp, const int* __restrict__ bs, int n, int Etot) {
  int i = blockIdx.x * 256 + threadIdx.x;
  if (i < n) rp[i] += bs[i >> 10];
  if (i == 0) rp[n] = Etot;
}

__global__ __launch_bounds__(256) void k_fill(const int* __restrict__ src, const int* __restrict__ dst,
                                              const int* __restrict__ rp, int* __restrict__ cnt,
                                              int* __restrict__ csr_src, int E) {
  int e = blockIdx.x * 256 + threadIdx.x;
  if (e < E) {
    int d = dst[e];
    int p = rp[d] + atomicAdd(&cnt[d], 1);
    csr_src[p] = src[e];
  }
}

// ---- combined layer-1 weights, split-bf16, stored in MFMA-fragment order ----
// v3 fragment index (64-col blocks): ((((cb*12 + kt)*4 + ni)*4 + lq)*16 + lr)*8 + j8
//   cb = col/64 (0..7), kt = k/32, ni = (col%64)/16, lq = (k%32)/8, lr = col%16, j8 = k%8
// Merged launch: blocks [0,385) -> G1 (off 0), [385,770) -> G2 (off 256)
__global__ __launch_bounds__(256) void k_precomb(const float* __restrict__ T1w, const float* __restrict__ T1b,
                                                 const float* __restrict__ T2w, const float* __restrict__ T2b,
                                                 const float* __restrict__ G1, const float* __restrict__ G2,
                                                 u16* __restrict__ Bh, u16* __restrict__ Bl,
                                                 float* __restrict__ cvec) {
  int bb = blockIdx.x;
  const float* G = (bb < 385) ? G1 : G2;
  int off = (bb < 385) ? 0 : 256;
  int r = (bb < 385) ? bb : bb - 385;  // 0..384: K index (384 rows) + 1 bias row
  int j = threadIdx.x;                 // col within 256
  float acc = 0.f;
  if (r < 256) {
    for (int m = 0; m < 128; m++) acc += T1w[r * 128 + m] * G[m * 256 + j];
  } else if (r < 384) {
    int rr = r - 256;
    for (int m = 0; m < 128; m++) acc += T2w[rr * 128 + m] * G[(128 + m) * 256 + j];
  } else {
    for (int m = 0; m < 128; m++) acc += T1b[m] * G[m * 256 + j] + T2b[m] * G[(128 + m) * 256 + j];
    cvec[off + j] = acc;
    return;
  }
  uint32 u = __float_as_uint(acc);
  uint32 hi = bf_rne(u);
  float rest = acc - __uint_as_float(hi << 16);
  uint32 lo = __float_as_uint(rest) >> 16;
  int k = r, colabs = off + j;
  int kt = k >> 5, lq = (k >> 3) & 3, j8 = k & 7;
  int cb = colabs >> 6, colr = colabs & 63, ni = colr >> 4, lr = colr & 15;
  size_t idx = ((size_t)(((cb * 12 + kt) * 4 + ni) * 4 + lq) * 16 + lr) * 8 + j8;
  Bh[idx] = (u16)hi;
  Bl[idx] = (u16)lo;
}

// async global->LDS, 16B per lane; LDS dest is wave-uniform base + lane*16
#define GLL(GP, LP)                                                     \
  __builtin_amdgcn_global_load_lds(                                     \
      (const __attribute__((address_space(1))) void*)(GP),              \
      (__attribute__((address_space(3))) void*)(LP), 16, 0, 0)

// ---- split-bf16 MFMA GEMM: C[N,512] = [sm|sp][N,384] @ Wc[384,512] + cvec; outputs fp16 ----
// v3: wave = 64 rows x 64 cols (4 m-tiles x 4 ni) -> each B ds_read pair feeds 12 MFMA,
// balancing LDS pipe vs MFMA pipe at the CU level. Block = 256 rows x 64 cols, cb in [0,8).
// 32 KB LDS double-buffered B (single barrier/stage), t-granular A register pipeline,
// XCD swizzle groups the 8 col-siblings of a row-panel on one XCD.
__global__ __launch_bounds__(256, 2) void k_gemm(const float* __restrict__ sm, const float* __restrict__ sp,
                                                 const u16* __restrict__ Bth, const u16* __restrict__ Btl,
                                                 const float* __restrict__ cvec, __half* __restrict__ fs,
                                                 __half* __restrict__ fd, int N) {
  __shared__ u16 BH[2][4096];  // 2 x 8 KB: per stage 2 k-tiles x 4 ni x 64 lanes x 8 halves
  __shared__ u16 BL[2][4096];
  int tid = threadIdx.x, w = tid >> 6, l = tid & 63;
  int lr = l & 15, lq = l >> 4;
  // bijective XCD swizzle: 8 col-siblings (cb=0..7, same rb) adjacent on one XCD
  int L = blockIdx.x;
  int x = L & 7, m5 = L >> 3;
  int cb = m5 & 7;
  int rb = x + 8 * (m5 >> 3);
  int col0 = cb * 64, row0 = rb * 256;
  if (row0 >= N) return;  // padded row-panels: whole block exits uniformly
  int rbase = row0 + w * 64 + lr;
  const float* psm[4];
  const float* psp[4];
#pragma unroll
  for (int m = 0; m < 4; m++) {
    int r = rbase + m * 16;
    int cix = r < N ? r : N - 1;
    psm[m] = sm + (size_t)cix * 256 + lq * 8;
    psp[m] = sp + (size_t)cix * 128 + lq * 8;
  }

  f32x4 acc[4][4];
#pragma unroll
  for (int mt = 0; mt < 4; mt++)
#pragma unroll
    for (int ni = 0; ni < 4; ni++) acc[mt][ni] = (f32x4){0.f, 0.f, 0.f, 0.f};

  // stage B(S) into LDS buffer BUF (identity map; per-wave uniform LDS base, per-lane global)
#define STAGE_B(S, BUF)                                                 \
  {                                                                     \
    size_t g0 = (size_t)(cb * 12 + (S)*2) * 2048;                       \
    _Pragma("unroll") for (int i = 0; i < 2; i++) {                     \
      int c = i * 256 + tid;                                            \
      int lb = (i * 4 + w) * 512;                                       \
      GLL(Bth + g0 + (size_t)c * 8, &BH[BUF][lb]);                      \
      GLL(Btl + g0 + (size_t)c * 8, &BL[BUF][lb]);                      \
    }                                                                   \
  }

  // load A phase P (P = st*2 + t, P in [0,12)) into D[0..7] (4 m-tiles x 2 float4)
#define LOADA(P, D)                                                     \
  {                                                                     \
    _Pragma("unroll") for (int m = 0; m < 4; m++) {                     \
      const float* _g = ((P) < 8) ? (psm[m] + (P)*32) : (psp[m] + ((P)-8) * 32); \
      D[2 * m] = *(const float4*)_g;                                    \
      D[2 * m + 1] = *(const float4*)(_g + 4);                          \
    }                                                                   \
  }

  // split + MFMA for t-phase T out of buffer BUF using raw A in D[0..7]
#define COMP(T, BUF, D)                                                 \
  {                                                                     \
    uint4 AH[4], AL[4];                                                 \
    _Pragma("unroll") for (int m = 0; m < 4; m++) {                     \
      split_trunc(D[2 * m].x, D[2 * m].y, AH[m].x, AL[m].x);            \
      split_trunc(D[2 * m].z, D[2 * m].w, AH[m].y, AL[m].y);            \
      split_trunc(D[2 * m + 1].x, D[2 * m + 1].y, AH[m].z, AL[m].z);    \
      split_trunc(D[2 * m + 1].z, D[2 * m + 1].w, AH[m].w, AL[m].w);    \
    }                                                                   \
    _Pragma("unroll") for (int ni = 0; ni < 4; ni++) {                  \
      int lo = (((T)*4 + ni) * 64 + l) * 8;                             \
      short8 bh = *(const short8*)&BH[BUF][lo];                         \
      short8 bl = *(const short8*)&BL[BUF][lo];                         \
      _Pragma("unroll") for (int m = 0; m < 4; m++) {                   \
        short8 ah = *(short8*)&AH[m], al = *(short8*)&AL[m];            \
        acc[m][ni] = __builtin_amdgcn_mfma_f32_16x16x32_bf16(ah, bh, acc[m][ni], 0, 0, 0); \
        acc[m][ni] = __builtin_amdgcn_mfma_f32_16x16x32_bf16(al, bh, acc[m][ni], 0, 0, 0); \
        acc[m][ni] = __builtin_amdgcn_mfma_f32_16x16x32_bf16(ah, bl, acc[m][ni], 0, 0, 0); \
      }                                                                 \
    }                                                                   \
  }

  float4 Ra[8], Rb[8];  // t-granular ping-pong raw A (even phases -> Ra, odd -> Rb)
  STAGE_B(0, 0);
  LOADA(0, Ra);

#pragma unroll
  for (int st = 0; st < 6; st++) {
    const int cu = st & 1, nx = cu ^ 1;
    __syncthreads();  // drains B(st) gl_lds + pending A loads; buf[nx] free to overwrite
    if (st < 5) STAGE_B(st + 1, nx);  // in flight for a full stage
    LOADA(2 * st + 1, Rb);            // t1 of this stage, covered by COMP(t0)
    COMP(0, cu, Ra);
    if (st < 5) LOADA(2 * st + 2, Ra);  // t0 of next stage, covered by COMP(t1)+barrier
    COMP(1, cu, Rb);
  }

  // epilogue: C row = lq*4 + reg, col = lane&15 per 16x16 tile; store fp16
#pragma unroll
  for (int mt = 0; mt < 4; mt++) {
    int rbr = row0 + w * 64 + mt * 16 + lq * 4;
#pragma unroll
    for (int ni = 0; ni < 4; ni++) {
      int c = col0 + ni * 16 + lr;
      float cv = cvec[c];
      __half* op = fs; int cc = c;
      if (c >= 256) { op = fd; cc = c - 256; }
#pragma unroll
      for (int r = 0; r < 4; r++) {
        int rr = rbr + r;
        if (rr < N) op[(size_t)rr * 256 + cc] = __float2half(acc[mt][ni][r] + cv);
      }
    }
  }
#undef STAGE_B
#undef LOADA
#undef COMP
}

// ---- layer-2 feature GEMM: fs/fd[N,256] = h[N,32] @ W[32,256] ----
__global__ __launch_bounds__(256) void k_feat2(const float* __restrict__ h, const float* __restrict__ Ws,
                                               const float* __restrict__ Wd, __half* __restrict__ fs,
                                               __half* __restrict__ fd, int N) {
  int j = threadIdx.x;
  int n0 = blockIdx.x * 32;
  float ws[32], wd[32];
#pragma unroll
  for (int k = 0; k < 32; k++) {
    ws[k] = Ws[k * 256 + j];
    wd[k] = Wd[k * 256 + j];
  }
  int nend = n0 + 32; if (nend > N) nend = N;
#pragma unroll 2
  for (int n = n0; n < nend; n++) {
    const float* hr = h + (size_t)n * 32;  // wave-uniform -> scalar loads
    float as = 0.f, ad = 0.f;
#pragma unroll
    for (int k = 0; k < 32; k++) {
      float hv = hr[k];
      as += hv * ws[k];
      ad += hv * wd[k];
    }
    fs[(size_t)n * 256 + j] = __float2half(as);
    fd[(size_t)n * 256 + j] = __float2half(ad);
  }
}

// ---- fused edge pass, packed-fp16 math: per-dst softmax + aggregate + bias (+elu) + head-mean ----
// 4-edge ILP with one-quad software pipeline (next quad's indices+gathers issued before
// computing current quad) to hide s_load->gather->use latency.
// one wave per dst node; lane L holds feature elements 4L..4L+3 (head = L>>3)
template <int FINAL>
__global__ __launch_bounds__(256) void k_edge(const uint2* __restrict__ fs, const uint2* __restrict__ fd,
                                              const int* __restrict__ csr_src, const int* __restrict__ rp,
                                              const float* __restrict__ attn, const float* __restrict__ bias,
                                              float* __restrict__ out, int N) {
  int n = blockIdx.x * 4 + (threadIdx.x >> 6);
  if (n >= N) return;
  int lane = threadIdx.x & 63;
  float4 av = ((const float4*)attn)[lane];
  H2 AV01, AV23, Y01, Y23;
  AV01.v = (f16x2){(_Float16)av.x, (_Float16)av.y};
  AV23.v = (f16x2){(_Float16)av.z, (_Float16)av.w};
  const f16x2 c02 = {(_Float16)0.2f, (_Float16)0.2f};
  uint2 yu = fd[(size_t)n * 64 + lane];
  Y01.u = yu.x; Y23.u = yu.y;
  int beg = rp[n], end = rp[n + 1];
  float den0 = 0.f, den1 = 0.f;
  float4 acc0 = {0.f, 0.f, 0.f, 0.f}, acc1 = {0.f, 0.f, 0.f, 0.f};

  auto edge1 = [&](uint2 xu, float& den, float4& acc) {
    H2 Xa, Xb; Xa.u = xu.x; Xb.u = xu.y;
    f16x2 ea = Xa.v + Y01.v, eb = Xb.v + Y23.v;
    f16x2 ta = __builtin_elementwise_max(ea, ea * c02);
    f16x2 tb = __builtin_elementwise_max(eb, eb * c02);
    float p = __builtin_amdgcn_fdot2(ta, AV01.v, 0.f, false);
    p = __builtin_amdgcn_fdot2(tb, AV23.v, p, false);
    p += __shfl_xor(p, 1, 64);
    p += __shfl_xor(p, 2, 64);
    p += __shfl_xor(p, 4, 64);
    float wgt = __expf(p);  // scores bounded: exp-safe without max shift
    den += wgt;
    acc.x += wgt * (float)Xa.v.x; acc.y += wgt * (float)Xa.v.y;
    acc.z += wgt * (float)Xb.v.x; acc.w += wgt * (float)Xb.v.y;
  };

  int e = beg;
  int nq = (end - beg) >> 2;
  if (nq > 0) {
    int s0 = csr_src[e], s1 = csr_src[e + 1], s2 = csr_src[e + 2], s3 = csr_src[e + 3];
    uint2 x0 = fs[(size_t)s0 * 64 + lane];
    uint2 x1 = fs[(size_t)s1 * 64 + lane];
    uint2 x2 = fs[(size_t)s2 * 64 + lane];
    uint2 x3 = fs[(size_t)s3 * 64 + lane];
    for (int q = 1; q < nq; q++) {
      int b2 = e + 4 * q;  // next quad (always in-bounds: q < nq)
      int t0 = csr_src[b2], t1 = csr_src[b2 + 1], t2 = csr_src[b2 + 2], t3 = csr_src[b2 + 3];
      uint2 y0 = fs[(size_t)t0 * 64 + lane];
      uint2 y1 = fs[(size_t)t1 * 64 + lane];
      uint2 y2 = fs[(size_t)t2 * 64 + lane];
      uint2 y3 = fs[(size_t)t3 * 64 + lane];
      edge1(x0, den0, acc0); edge1(x1, den1, acc1);
      edge1(x2, den0, acc0); edge1(x3, den1, acc1);
      x0 = y0; x1 = y1; x2 = y2; x3 = y3;
    }
    edge1(x0, den0, acc0); edge1(x1, den1, acc1);
    edge1(x2, den0, acc0); edge1(x3, den1, acc1);
    e += 4 * nq;
  }
  for (; e < end; e++) {
    int s0 = csr_src[e];
    uint2 xu = fs[(size_t)s0 * 64 + lane];
    edge1(xu, den0, acc0);
  }

  float4 acc = {acc0.x + acc1.x, acc0.y + acc1.y, acc0.z + acc1.z, acc0.w + acc1.w};
  float invd = 1.f / (den0 + den1);
  float4 b = ((const float4*)bias)[lane];
  acc.x = acc.x * invd + b.x;
  acc.y = acc.y * invd + b.y;
  acc.z = acc.z * invd + b.z;
  acc.w = acc.w * invd + b.w;
  if (!FINAL) {
    acc.x = acc.x > 0.f ? acc.x : expm1f(acc.x);
    acc.y = acc.y > 0.f ? acc.y : expm1f(acc.y);
    acc.z = acc.z > 0.f ? acc.z : expm1f(acc.z);
    acc.w = acc.w > 0.f ? acc.w : expm1f(acc.w);
  }
#pragma unroll
  for (int mask = 8; mask <= 32; mask <<= 1) {
    acc.x += __shfl_xor(acc.x, mask, 64);
    acc.y += __shfl_xor(acc.y, mask, 64);
    acc.z += __shfl_xor(acc.z, mask, 64);
    acc.w += __shfl_xor(acc.w, mask, 64);
  }
  if (lane < 8) {
    float4 o = {acc.x * 0.125f, acc.y * 0.125f, acc.z * 0.125f, acc.w * 0.125f};
    ((float4*)out)[(size_t)n * 8 + lane] = o;
  }
}

extern "C" void kernel_launch(void* const* d_in, const int* in_sizes, int n_in,
                              void* d_out, int out_size, void* d_ws, size_t ws_size,
                              hipStream_t stream) {
  const float* sm  = (const float*)d_in[0];
  const float* sp  = (const float*)d_in[1];
  const int*   src = (const int*)d_in[2];
  const int*   dst = (const int*)d_in[3];
  const float* T1w = (const float*)d_in[4];
  const float* T1b = (const float*)d_in[5];
  const float* T2w = (const float*)d_in[6];
  const float* T2b = (const float*)d_in[7];
  const float* g1sw = (const float*)d_in[8];
  const float* g1dw = (const float*)d_in[9];
  const float* g1a  = (const float*)d_in[10];
  const float* g1b  = (const float*)d_in[11];
  const float* g2sw = (const float*)d_in[12];
  const float* g2dw = (const float*)d_in[13];
  const float* g2a  = (const float*)d_in[14];
  const float* g2b  = (const float*)d_in[15];
  const int N = in_sizes[1] / 128;  // sp_feats is [N,128]
  const int E = in_sizes[2];
  float* out = (float*)d_out;

  size_t off = 0;
  char* wsb = (char*)d_ws;
  auto alloc = [&](size_t bytes) -> void* {
    void* p = wsb + off;
    off += (bytes + 255) & ~(size_t)255;
    return p;
  };
  u16* Bth = (u16*)alloc((size_t)512 * 384 * 2);
  u16* Btl = (u16*)alloc((size_t)512 * 384 * 2);
  float* cvec  = (float*)alloc(512 * 4);
  int* deg     = (int*)alloc((size_t)N * 4);
  int* cnt     = (int*)alloc((size_t)N * 4);
  int* row_ptr = (int*)alloc((size_t)(N + 1) * 4);
  int* blksum  = (int*)alloc(4096 * 4);
  int* csr_src = (int*)alloc((size_t)E * 4);
  __half* fs   = (__half*)alloc((size_t)N * 256 * 2);
  __half* fd   = (__half*)alloc((size_t)N * 256 * 2);
  float* hmid  = (float*)alloc((size_t)N * 32 * 4);
  (void)ws_size; (void)n_in; (void)out_size;

  (void)hipMemsetAsync(deg, 0, (size_t)N * 4, stream);
  (void)hipMemsetAsync(cnt, 0, (size_t)N * 4, stream);

  // CSR by destination (shared by both layers)
  k_deg<<<(E + 255) / 256, 256, 0, stream>>>(dst, deg, E);
  int nblk = (N + 1023) / 1024;
  k_blkscan<<<nblk, 256, 0, stream>>>(deg, row_ptr, blksum, N);
  k_scan_top<<<1, 64, 0, stream>>>(blksum, nblk);
  k_addoff<<<(N + 255) / 256, 256, 0, stream>>>(row_ptr, blksum, N, E);
  k_fill<<<(E + 255) / 256, 256, 0, stream>>>(src, dst, row_ptr, cnt, csr_src, E);

  // fold T1/T2 into layer-1 weights, split-bf16, fragment-ordered (both halves, one launch)
  k_precomb<<<770, 256, 0, stream>>>(T1w, T1b, T2w, T2b, g1sw, g1dw, Bth, Btl, cvec);

  // layer 1: 256-row panels x 8 col-blocks, XCD-swizzled; panels padded to a multiple of 8
  int rbs = (N + 255) / 256;
  int rbp = (rbs + 7) & ~7;
  k_gemm<<<dim3(rbp * 8), 256, 0, stream>>>(sm, sp, Bth, Btl, cvec, fs, fd, N);
  k_edge<0><<<(N + 3) / 4, 256, 0, stream>>>((const uint2*)fs, (const uint2*)fd, csr_src, row_ptr, g1a, g1b, hmid, N);

  // layer 2
  k_feat2<<<(N + 31) / 32, 256, 0, stream>>>(hmid, g2sw, g2dw, fs, fd, N);
  k_edge<1><<<(N + 3) / 4, 256, 0, stream>>>((const uint2*)fs, (const uint2*)fd, csr_src, row_ptr, g2a, g2b, out, N);
}

// Round 4
// 476.612 us; speedup vs baseline: 1.0857x; 1.0857x over previous
//
#include <hip/hip_runtime.h>
#include <hip/hip_fp16.h>

// N=50000 nodes, E=850000 edges, H=8 heads, D=32, H*D=256, IN=128, SM=256, SP=128

typedef unsigned int uint32;
typedef unsigned short u16;
typedef short short8 __attribute__((ext_vector_type(8)));
typedef float f32x4 __attribute__((ext_vector_type(4)));
typedef _Float16 f16x2 __attribute__((ext_vector_type(2)));

union H2 { f16x2 v; uint32 u; };

// fp32 -> bf16 round-to-nearest-even (low 16 bits)
__device__ __forceinline__ uint32 bf_rne(uint32 u) { return (u + 0x7fffu + ((u >> 16) & 1u)) >> 16; }

// cheap split: hi = trunc-bf16(a), lo = trunc-bf16(a - hi); packed pairs via v_perm
__device__ __forceinline__ void split_trunc(float a, float b, uint32& h, uint32& l) {
  uint32 ua = __float_as_uint(a), ub = __float_as_uint(b);
  h = __builtin_amdgcn_perm(ub, ua, 0x07060302u);  // [ub.hi16 | ua.hi16]
  float ra = a - __uint_as_float(ua & 0xffff0000u);
  float rb = b - __uint_as_float(ub & 0xffff0000u);
  l = __builtin_amdgcn_perm(__float_as_uint(rb), __float_as_uint(ra), 0x07060302u);
}

__device__ __forceinline__ int wave_incl_scan(int x) {
  int lane = threadIdx.x & 63;
#pragma unroll
  for (int off = 1; off < 64; off <<= 1) {
    int t = __shfl_up(x, off, 64);
    if (lane >= off) x += t;
  }
  return x;
}

// ---------------- CSR build ----------------
__global__ __launch_bounds__(256) void k_deg(const int* __restrict__ dst, int* __restrict__ deg, int E) {
  int e = blockIdx.x * 256 + threadIdx.x;
  if (e < E) atomicAdd(&deg[dst[e]], 1);
}

__global__ __launch_bounds__(256) void k_blkscan(const int* __restrict__ in, int* __restrict__ out,
                                                 int* __restrict__ blksum, int n) {
  __shared__ int wsum[4];
  int tid = threadIdx.x;
  int i0 = blockIdx.x * 1024 + tid * 4;
  int v0 = 0, v1 = 0, v2 = 0, v3 = 0;
  if (i0 + 3 < n) {
    int4 t = *(const int4*)(in + i0);
    v0 = t.x; v1 = t.y; v2 = t.z; v3 = t.w;
  } else {
    if (i0 < n) v0 = in[i0];
    if (i0 + 1 < n) v1 = in[i0 + 1];
    if (i0 + 2 < n) v2 = in[i0 + 2];
    if (i0 + 3 < n) v3 = in[i0 + 3];
  }
  int ts = v0 + v1 + v2 + v3;
  int incl = wave_incl_scan(ts);
  int lane = tid & 63, wid = tid >> 6;
  if (lane == 63) wsum[wid] = incl;
  __syncthreads();
  if (tid == 0) {
    int a = wsum[0], b = wsum[1], c = wsum[2], d = wsum[3];
    wsum[0] = 0; wsum[1] = a; wsum[2] = a + b; wsum[3] = a + b + c;
    blksum[blockIdx.x] = a + b + c + d;
  }
  __syncthreads();
  int excl = wsum[wid] + incl - ts;
  if (i0 + 3 < n) {
    int4 o; o.x = excl; o.y = excl + v0; o.z = excl + v0 + v1; o.w = excl + v0 + v1 + v2;
    *(int4*)(out + i0) = o;
  } else {
    if (i0 < n) out[i0] = excl;
    if (i0 + 1 < n) out[i0 + 1] = excl + v0;
    if (i0 + 2 < n) out[i0 + 2] = excl + v0 + v1;
    if (i0 + 3 < n) out[i0 + 3] = excl + v0 + v1 + v2;
  }
}

__global__ void k_scan_top(int* __restrict__ bs, int G) {
  int lane = threadIdx.x;  // 64 threads
  int base = 0;
  for (int s = 0; s < G; s += 64) {
    int i = s + lane;
    int v = (i < G) ? bs[i] : 0;
    int incl = wave_incl_scan(v);
    if (i < G) bs[i] = base + incl - v;
    base += __shfl(incl, 63, 64);
  }
}

__global__ __launch_bounds__(256) void k_addoff(int* __restrict__ rp, const int* __restrict__ bs, int n, int Etot) {
  int i = blockIdx.x * 256 + threadIdx.x;
  if (i < n) rp[i] += bs[i >> 10];
  if (i == 0) rp[n] = Etot;
}

__global__ __launch_bounds__(256) void k_fill(const int* __restrict__ src, const int* __restrict__ dst,
                                              const int* __restrict__ rp, int* __restrict__ cnt,
                                              int* __restrict__ csr_src, int E) {
  int e = blockIdx.x * 256 + threadIdx.x;
  if (e < E) {
    int d = dst[e];
    int p = rp[d] + atomicAdd(&cnt[d], 1);
    csr_src[p] = src[e];
  }
}

// ---- combined layer-1 weights, split-bf16, stored in MFMA-fragment order ----
// Bfrag index: ((((cb*12 + kt)*8 + ni)*4 + lq)*16 + lr)*8 + j8
//   cb = col/128, kt = k/32, ni = (col%128)/16, lq = (k%32)/8, lr = col%16, j8 = k%8
// Merged launch: blocks [0,385) -> G1 (off 0), [385,770) -> G2 (off 256)
__global__ __launch_bounds__(256) void k_precomb(const float* __restrict__ T1w, const float* __restrict__ T1b,
                                                 const float* __restrict__ T2w, const float* __restrict__ T2b,
                                                 const float* __restrict__ G1, const float* __restrict__ G2,
                                                 u16* __restrict__ Bh, u16* __restrict__ Bl,
                                                 float* __restrict__ cvec) {
  int bb = blockIdx.x;
  const float* G = (bb < 385) ? G1 : G2;
  int off = (bb < 385) ? 0 : 256;
  int r = (bb < 385) ? bb : bb - 385;  // 0..384: K index (384 rows) + 1 bias row
  int j = threadIdx.x;                 // col within 256
  float acc = 0.f;
  if (r < 256) {
    for (int m = 0; m < 128; m++) acc += T1w[r * 128 + m] * G[m * 256 + j];
  } else if (r < 384) {
    int rr = r - 256;
    for (int m = 0; m < 128; m++) acc += T2w[rr * 128 + m] * G[(128 + m) * 256 + j];
  } else {
    for (int m = 0; m < 128; m++) acc += T1b[m] * G[m * 256 + j] + T2b[m] * G[(128 + m) * 256 + j];
    cvec[off + j] = acc;
    return;
  }
  uint32 u = __float_as_uint(acc);
  uint32 hi = bf_rne(u);
  float rest = acc - __uint_as_float(hi << 16);
  uint32 lo = __float_as_uint(rest) >> 16;
  int k = r, colabs = off + j;
  int kt = k >> 5, lq = (k >> 3) & 3, j8 = k & 7;
  int cb = colabs >> 7, colr = colabs & 127, ni = colr >> 4, lr = colr & 15;
  size_t idx = ((size_t)(((cb * 12 + kt) * 8 + ni) * 4 + lq) * 16 + lr) * 8 + j8;
  Bh[idx] = (u16)hi;
  Bl[idx] = (u16)lo;
}

// async global->LDS, 16B per lane; LDS dest is wave-uniform base + lane*16
#define GLL(GP, LP)                                                     \
  __builtin_amdgcn_global_load_lds(                                     \
      (const __attribute__((address_space(1))) void*)(GP),              \
      (__attribute__((address_space(3))) void*)(LP), 16, 0, 0)

// ---- split-bf16 MFMA GEMM: C[N,512] = [sm|sp][N,384] @ Wc[384,512] + cvec; outputs fp16 ----
// v4: r0 geometry (128x128, 2 m-tiles x 8 ni per wave) + 4 blocks/CU (VGPR<=64 + 64 AGPR,
// 32 KB LDS) for TLP-based latency hiding + XCD-sibling swizzle (proven: FETCH 155->45 MB)
// + async gl_lds B staging, BK=32 double-buffered, ONE barrier per k-tile.
// A loads issued BEFORE the B GLLs each stage so the split's vmcnt wait retires only A,
// keeping next-stage B staging in flight through the MFMA block.
__global__ __launch_bounds__(256, 4) void k_gemm(const float* __restrict__ sm, const float* __restrict__ sp,
                                                 const u16* __restrict__ Bth, const u16* __restrict__ Btl,
                                                 const float* __restrict__ cvec, __half* __restrict__ fs,
                                                 __half* __restrict__ fd, int N) {
  __shared__ u16 BH[2][4096];  // 2 x 8 KB: per stage 1 k-tile x 8 ni x 64 lanes x 8 halves
  __shared__ u16 BL[2][4096];
  int tid = threadIdx.x, w = tid >> 6, l = tid & 63;
  int lr = l & 15, lq = l >> 4;
  // bijective XCD-sibling swizzle: the 4 col-siblings of a row-panel share L%8 -> same XCD
  int L = blockIdx.x;
  int x = L & 7, m = L >> 3;
  int cb = m & 3;
  int rb = x + 8 * (m >> 2);
  int col0 = cb * 128, row0 = rb * 128;
  if (row0 >= N) return;  // padded row-panels: whole block exits uniformly
  int r0 = row0 + w * 32 + lr;
  int r1 = r0 + 16;
  int c0 = r0 < N ? r0 : N - 1;
  int c1 = r1 < N ? r1 : N - 1;
  const float* psm0 = sm + (size_t)c0 * 256 + lq * 8;
  const float* psm1 = sm + (size_t)c1 * 256 + lq * 8;
  const float* psp0 = sp + (size_t)c0 * 128 + lq * 8;
  const float* psp1 = sp + (size_t)c1 * 128 + lq * 8;

  f32x4 acc[2][8];
#pragma unroll
  for (int mt = 0; mt < 2; mt++)
#pragma unroll
    for (int ni = 0; ni < 8; ni++) acc[mt][ni] = (f32x4){0.f, 0.f, 0.f, 0.f};

  // stage B k-tile S into LDS buffer BUF (identity map, wave-uniform LDS base)
#define STAGE_B(S, BUF)                                                 \
  {                                                                     \
    size_t g0 = (size_t)(cb * 12 + (S)) * 4096;                         \
    _Pragma("unroll") for (int i = 0; i < 2; i++) {                     \
      int c = i * 256 + tid;                                            \
      int lb = (i * 4 + w) * 512;                                       \
      GLL(Bth + g0 + (size_t)c * 8, &BH[BUF][lb]);                      \
      GLL(Btl + g0 + (size_t)c * 8, &BL[BUF][lb]);                      \
    }                                                                   \
  }

  STAGE_B(0, 0);

#pragma unroll
  for (int st = 0; st < 12; st++) {
    const int cu = st & 1, nx = cu ^ 1;
    __syncthreads();  // drains B(st) gl_lds; buf[nx] free to overwrite
    // A loads for this k-tile FIRST (so their vmcnt wait doesn't drain the GLLs below)
    const float* ga0 = (st < 8) ? (psm0 + st * 32) : (psp0 + (st - 8) * 32);
    const float* ga1 = (st < 8) ? (psm1 + st * 32) : (psp1 + (st - 8) * 32);
    float4 v00 = *(const float4*)(ga0);
    float4 v01 = *(const float4*)(ga0 + 4);
    float4 v10 = *(const float4*)(ga1);
    float4 v11 = *(const float4*)(ga1 + 4);
    if (st < 11) STAGE_B(st + 1, nx);  // in flight through the MFMA block
    uint4 H0, L0, H1, L1;
    split_trunc(v00.x, v00.y, H0.x, L0.x);
    split_trunc(v00.z, v00.w, H0.y, L0.y);
    split_trunc(v01.x, v01.y, H0.z, L0.z);
    split_trunc(v01.z, v01.w, H0.w, L0.w);
    split_trunc(v10.x, v10.y, H1.x, L1.x);
    split_trunc(v10.z, v10.w, H1.y, L1.y);
    split_trunc(v11.x, v11.y, H1.z, L1.z);
    split_trunc(v11.z, v11.w, H1.w, L1.w);
    short8 a0h = *(short8*)&H0, a0l = *(short8*)&L0;
    short8 a1h = *(short8*)&H1, a1l = *(short8*)&L1;
#pragma unroll
    for (int ni = 0; ni < 8; ni++) {
      int lo = (ni * 64 + l) * 8;  // lane-contiguous: zero bank conflicts
      short8 bh = *(const short8*)&BH[cu][lo];
      short8 bl = *(const short8*)&BL[cu][lo];
      acc[0][ni] = __builtin_amdgcn_mfma_f32_16x16x32_bf16(a0h, bh, acc[0][ni], 0, 0, 0);
      acc[0][ni] = __builtin_amdgcn_mfma_f32_16x16x32_bf16(a0l, bh, acc[0][ni], 0, 0, 0);
      acc[0][ni] = __builtin_amdgcn_mfma_f32_16x16x32_bf16(a0h, bl, acc[0][ni], 0, 0, 0);
      acc[1][ni] = __builtin_amdgcn_mfma_f32_16x16x32_bf16(a1h, bh, acc[1][ni], 0, 0, 0);
      acc[1][ni] = __builtin_amdgcn_mfma_f32_16x16x32_bf16(a1l, bh, acc[1][ni], 0, 0, 0);
      acc[1][ni] = __builtin_amdgcn_mfma_f32_16x16x32_bf16(a1h, bl, acc[1][ni], 0, 0, 0);
    }
  }

  // epilogue: C row = lq*4 + reg, col = lane&15 per 16x16 tile; store fp16
#pragma unroll
  for (int mt = 0; mt < 2; mt++) {
    int rbr = row0 + w * 32 + mt * 16 + lq * 4;
#pragma unroll
    for (int ni = 0; ni < 8; ni++) {
      int c = col0 + ni * 16 + lr;
      float cv = cvec[c];
      __half* op = fs; int cc = c;
      if (c >= 256) { op = fd; cc = c - 256; }
#pragma unroll
      for (int r = 0; r < 4; r++) {
        int rr = rbr + r;
        if (rr < N) op[(size_t)rr * 256 + cc] = __float2half(acc[mt][ni][r] + cv);
      }
    }
  }
#undef STAGE_B
}

// ---- layer-2 feature GEMM: fs/fd[N,256] = h[N,32] @ W[32,256] ----
__global__ __launch_bounds__(256) void k_feat2(const float* __restrict__ h, const float* __restrict__ Ws,
                                               const float* __restrict__ Wd, __half* __restrict__ fs,
                                               __half* __restrict__ fd, int N) {
  int j = threadIdx.x;
  int n0 = blockIdx.x * 32;
  float ws[32], wd[32];
#pragma unroll
  for (int k = 0; k < 32; k++) {
    ws[k] = Ws[k * 256 + j];
    wd[k] = Wd[k * 256 + j];
  }
  int nend = n0 + 32; if (nend > N) nend = N;
#pragma unroll 2
  for (int n = n0; n < nend; n++) {
    const float* hr = h + (size_t)n * 32;  // wave-uniform -> scalar loads
    float as = 0.f, ad = 0.f;
#pragma unroll
    for (int k = 0; k < 32; k++) {
      float hv = hr[k];
      as += hv * ws[k];
      ad += hv * wd[k];
    }
    fs[(size_t)n * 256 + j] = __float2half(as);
    fd[(size_t)n * 256 + j] = __float2half(ad);
  }
}

// ---- fused edge pass, packed-fp16 math: per-dst softmax + aggregate + bias (+elu) + head-mean ----
// 4-edge ILP with one-quad software pipeline (next quad's indices+gathers issued before
// computing current quad) to hide s_load->gather->use latency.
// one wave per dst node; lane L holds feature elements 4L..4L+3 (head = L>>3)
template <int FINAL>
__global__ __launch_bounds__(256) void k_edge(const uint2* __restrict__ fs, const uint2* __restrict__ fd,
                                              const int* __restrict__ csr_src, const int* __restrict__ rp,
                                              const float* __restrict__ attn, const float* __restrict__ bias,
                                              float* __restrict__ out, int N) {
  int n = blockIdx.x * 4 + (threadIdx.x >> 6);
  if (n >= N) return;
  int lane = threadIdx.x & 63;
  float4 av = ((const float4*)attn)[lane];
  H2 AV01, AV23, Y01, Y23;
  AV01.v = (f16x2){(_Float16)av.x, (_Float16)av.y};
  AV23.v = (f16x2){(_Float16)av.z, (_Float16)av.w};
  const f16x2 c02 = {(_Float16)0.2f, (_Float16)0.2f};
  uint2 yu = fd[(size_t)n * 64 + lane];
  Y01.u = yu.x; Y23.u = yu.y;
  int beg = rp[n], end = rp[n + 1];
  float den0 = 0.f, den1 = 0.f;
  float4 acc0 = {0.f, 0.f, 0.f, 0.f}, acc1 = {0.f, 0.f, 0.f, 0.f};

  auto edge1 = [&](uint2 xu, float& den, float4& acc) {
    H2 Xa, Xb; Xa.u = xu.x; Xb.u = xu.y;
    f16x2 ea = Xa.v + Y01.v, eb = Xb.v + Y23.v;
    f16x2 ta = __builtin_elementwise_max(ea, ea * c02);
    f16x2 tb = __builtin_elementwise_max(eb, eb * c02);
    float p = __builtin_amdgcn_fdot2(ta, AV01.v, 0.f, false);
    p = __builtin_amdgcn_fdot2(tb, AV23.v, p, false);
    p += __shfl_xor(p, 1, 64);
    p += __shfl_xor(p, 2, 64);
    p += __shfl_xor(p, 4, 64);
    float wgt = __expf(p);  // scores bounded: exp-safe without max shift
    den += wgt;
    acc.x += wgt * (float)Xa.v.x; acc.y += wgt * (float)Xa.v.y;
    acc.z += wgt * (float)Xb.v.x; acc.w += wgt * (float)Xb.v.y;
  };

  int e = beg;
  int nq = (end - beg) >> 2;
  if (nq > 0) {
    int s0 = csr_src[e], s1 = csr_src[e + 1], s2 = csr_src[e + 2], s3 = csr_src[e + 3];
    uint2 x0 = fs[(size_t)s0 * 64 + lane];
    uint2 x1 = fs[(size_t)s1 * 64 + lane];
    uint2 x2 = fs[(size_t)s2 * 64 + lane];
    uint2 x3 = fs[(size_t)s3 * 64 + lane];
    for (int q = 1; q < nq; q++) {
      int b2 = e + 4 * q;  // next quad (always in-bounds: q < nq)
      int t0 = csr_src[b2], t1 = csr_src[b2 + 1], t2 = csr_src[b2 + 2], t3 = csr_src[b2 + 3];
      uint2 y0 = fs[(size_t)t0 * 64 + lane];
      uint2 y1 = fs[(size_t)t1 * 64 + lane];
      uint2 y2 = fs[(size_t)t2 * 64 + lane];
      uint2 y3 = fs[(size_t)t3 * 64 + lane];
      edge1(x0, den0, acc0); edge1(x1, den1, acc1);
      edge1(x2, den0, acc0); edge1(x3, den1, acc1);
      x0 = y0; x1 = y1; x2 = y2; x3 = y3;
    }
    edge1(x0, den0, acc0); edge1(x1, den1, acc1);
    edge1(x2, den0, acc0); edge1(x3, den1, acc1);
    e += 4 * nq;
  }
  for (; e < end; e++) {
    int s0 = csr_src[e];
    uint2 xu = fs[(size_t)s0 * 64 + lane];
    edge1(xu, den0, acc0);
  }

  float4 acc = {acc0.x + acc1.x, acc0.y + acc1.y, acc0.z + acc1.z, acc0.w + acc1.w};
  float invd = 1.f / (den0 + den1);
  float4 b = ((const float4*)bias)[lane];
  acc.x = acc.x * invd + b.x;
  acc.y = acc.y * invd + b.y;
  acc.z = acc.z * invd + b.z;
  acc.w = acc.w * invd + b.w;
  if (!FINAL) {
    acc.x = acc.x > 0.f ? acc.x : expm1f(acc.x);
    acc.y = acc.y > 0.f ? acc.y : expm1f(acc.y);
    acc.z = acc.z > 0.f ? acc.z : expm1f(acc.z);
    acc.w = acc.w > 0.f ? acc.w : expm1f(acc.w);
  }
#pragma unroll
  for (int mask = 8; mask <= 32; mask <<= 1) {
    acc.x += __shfl_xor(acc.x, mask, 64);
    acc.y += __shfl_xor(acc.y, mask, 64);
    acc.z += __shfl_xor(acc.z, mask, 64);
    acc.w += __shfl_xor(acc.w, mask, 64);
  }
  if (lane < 8) {
    float4 o = {acc.x * 0.125f, acc.y * 0.125f, acc.z * 0.125f, acc.w * 0.125f};
    ((float4*)out)[(size_t)n * 8 + lane] = o;
  }
}

extern "C" void kernel_launch(void* const* d_in, const int* in_sizes, int n_in,
                              void* d_out, int out_size, void* d_ws, size_t ws_size,
                              hipStream_t stream) {
  const float* sm  = (const float*)d_in[0];
  const float* sp  = (const float*)d_in[1];
  const int*   src = (const int*)d_in[2];
  const int*   dst = (const int*)d_in[3];
  const float* T1w = (const float*)d_in[4];
  const float* T1b = (const float*)d_in[5];
  const float* T2w = (const float*)d_in[6];
  const float* T2b = (const float*)d_in[7];
  const float* g1sw = (const float*)d_in[8];
  const float* g1dw = (const float*)d_in[9];
  const float* g1a  = (const float*)d_in[10];
  const float* g1b  = (const float*)d_in[11];
  const float* g2sw = (const float*)d_in[12];
  const float* g2dw = (const float*)d_in[13];
  const float* g2a  = (const float*)d_in[14];
  const float* g2b  = (const float*)d_in[15];
  const int N = in_sizes[1] / 128;  // sp_feats is [N,128]
  const int E = in_sizes[2];
  float* out = (float*)d_out;

  size_t off = 0;
  char* wsb = (char*)d_ws;
  auto alloc = [&](size_t bytes) -> void* {
    void* p = wsb + off;
    off += (bytes + 255) & ~(size_t)255;
    return p;
  };
  u16* Bth = (u16*)alloc((size_t)512 * 384 * 2);
  u16* Btl = (u16*)alloc((size_t)512 * 384 * 2);
  float* cvec  = (float*)alloc(512 * 4);
  int* deg     = (int*)alloc((size_t)N * 4);
  int* cnt     = (int*)alloc((size_t)N * 4);
  int* row_ptr = (int*)alloc((size_t)(N + 1) * 4);
  int* blksum  = (int*)alloc(4096 * 4);
  int* csr_src = (int*)alloc((size_t)E * 4);
  __half* fs   = (__half*)alloc((size_t)N * 256 * 2);
  __half* fd   = (__half*)alloc((size_t)N * 256 * 2);
  float* hmid  = (float*)alloc((size_t)N * 32 * 4);
  (void)ws_size; (void)n_in; (void)out_size;

  (void)hipMemsetAsync(deg, 0, (size_t)N * 4, stream);
  (void)hipMemsetAsync(cnt, 0, (size_t)N * 4, stream);

  // CSR by destination (shared by both layers)
  k_deg<<<(E + 255) / 256, 256, 0, stream>>>(dst, deg, E);
  int nblk = (N + 1023) / 1024;
  k_blkscan<<<nblk, 256, 0, stream>>>(deg, row_ptr, blksum, N);
  k_scan_top<<<1, 64, 0, stream>>>(blksum, nblk);
  k_addoff<<<(N + 255) / 256, 256, 0, stream>>>(row_ptr, blksum, N, E);
  k_fill<<<(E + 255) / 256, 256, 0, stream>>>(src, dst, row_ptr, cnt, csr_src, E);

  // fold T1/T2 into layer-1 weights, split-bf16, fragment-ordered (both halves, one launch)
  k_precomb<<<770, 256, 0, stream>>>(T1w, T1b, T2w, T2b, g1sw, g1dw, Bth, Btl, cvec);

  // layer 1: 128-row panels x 4 col-blocks, XCD-swizzled; panels padded to a multiple of 8
  int rbs = (N + 127) / 128;
  int rbp = (rbs + 7) & ~7;
  k_gemm<<<dim3(rbp * 4), 256, 0, stream>>>(sm, sp, Bth, Btl, cvec, fs, fd, N);
  k_edge<0><<<(N + 3) / 4, 256, 0, stream>>>((const uint2*)fs, (const uint2*)fd, csr_src, row_ptr, g1a, g1b, hmid, N);

  // layer 2
  k_feat2<<<(N + 31) / 32, 256, 0, stream>>>(hmid, g2sw, g2dw, fs, fd, N);
  k_edge<1><<<(N + 3) / 4, 256, 0, stream>>>((const uint2*)fs, (const uint2*)fd, csr_src, row_ptr, g2a, g2b, out, N);
}

// Round 5
// 462.040 us; speedup vs baseline: 1.1199x; 1.0315x over previous
//
#include <hip/hip_runtime.h>
#include <hip/hip_fp16.h>

// N=50000 nodes, E=850000 edges, H=8 heads, D=32, H*D=256, IN=128, SM=256, SP=128

typedef unsigned int uint32;
typedef unsigned short u16;
typedef float f32x4 __attribute__((ext_vector_type(4)));
typedef _Float16 f16x2 __attribute__((ext_vector_type(2)));
typedef _Float16 f16x8 __attribute__((ext_vector_type(8)));

union H2 { f16x2 v; uint32 u; };

__device__ __forceinline__ int wave_incl_scan(int x) {
  int lane = threadIdx.x & 63;
#pragma unroll
  for (int off = 1; off < 64; off <<= 1) {
    int t = __shfl_up(x, off, 64);
    if (lane >= off) x += t;
  }
  return x;
}

// ---------------- CSR build ----------------
__global__ __launch_bounds__(256) void k_deg(const int* __restrict__ dst, int* __restrict__ deg, int E) {
  int e = blockIdx.x * 256 + threadIdx.x;
  if (e < E) atomicAdd(&deg[dst[e]], 1);
}

__global__ __launch_bounds__(256) void k_blkscan(const int* __restrict__ in, int* __restrict__ out,
                                                 int* __restrict__ blksum, int n) {
  __shared__ int wsum[4];
  int tid = threadIdx.x;
  int i0 = blockIdx.x * 1024 + tid * 4;
  int v0 = 0, v1 = 0, v2 = 0, v3 = 0;
  if (i0 + 3 < n) {
    int4 t = *(const int4*)(in + i0);
    v0 = t.x; v1 = t.y; v2 = t.z; v3 = t.w;
  } else {
    if (i0 < n) v0 = in[i0];
    if (i0 + 1 < n) v1 = in[i0 + 1];
    if (i0 + 2 < n) v2 = in[i0 + 2];
    if (i0 + 3 < n) v3 = in[i0 + 3];
  }
  int ts = v0 + v1 + v2 + v3;
  int incl = wave_incl_scan(ts);
  int lane = tid & 63, wid = tid >> 6;
  if (lane == 63) wsum[wid] = incl;
  __syncthreads();
  if (tid == 0) {
    int a = wsum[0], b = wsum[1], c = wsum[2], d = wsum[3];
    wsum[0] = 0; wsum[1] = a; wsum[2] = a + b; wsum[3] = a + b + c;
    blksum[blockIdx.x] = a + b + c + d;
  }
  __syncthreads();
  int excl = wsum[wid] + incl - ts;
  if (i0 + 3 < n) {
    int4 o; o.x = excl; o.y = excl + v0; o.z = excl + v0 + v1; o.w = excl + v0 + v1 + v2;
    *(int4*)(out + i0) = o;
  } else {
    if (i0 < n) out[i0] = excl;
    if (i0 + 1 < n) out[i0 + 1] = excl + v0;
    if (i0 + 2 < n) out[i0 + 2] = excl + v0 + v1;
    if (i0 + 3 < n) out[i0 + 3] = excl + v0 + v1 + v2;
  }
}

__global__ void k_scan_top(int* __restrict__ bs, int G) {
  int lane = threadIdx.x;  // 64 threads
  int base = 0;
  for (int s = 0; s < G; s += 64) {
    int i = s + lane;
    int v = (i < G) ? bs[i] : 0;
    int incl = wave_incl_scan(v);
    if (i < G) bs[i] = base + incl - v;
    base += __shfl(incl, 63, 64);
  }
}

__global__ __launch_bounds__(256) void k_addoff(int* __restrict__ rp, const int* __restrict__ bs, int n, int Etot) {
  int i = blockIdx.x * 256 + threadIdx.x;
  if (i < n) rp[i] += bs[i >> 10];
  if (i == 0) rp[n] = Etot;
}

__global__ __launch_bounds__(256) void k_fill(const int* __restrict__ src, const int* __restrict__ dst,
                                              const int* __restrict__ rp, int* __restrict__ cnt,
                                              int* __restrict__ csr_src, int E) {
  int e = blockIdx.x * 256 + threadIdx.x;
  if (e < E) {
    int d = dst[e];
    int p = rp[d] + atomicAdd(&cnt[d], 1);
    csr_src[p] = src[e];
  }
}

// ---- combined layer-1 weights, fp16, stored in MFMA-fragment order ----
// Bfrag index: ((((cb*12 + kt)*8 + ni)*4 + lq)*16 + lr)*8 + j8
//   cb = col/128, kt = k/32, ni = (col%128)/16, lq = (k%32)/8, lr = col%16, j8 = k%8
// Merged launch: blocks [0,385) -> G1 (off 0), [385,770) -> G2 (off 256)
__global__ __launch_bounds__(256) void k_precomb(const float* __restrict__ T1w, const float* __restrict__ T1b,
                                                 const float* __restrict__ T2w, const float* __restrict__ T2b,
                                                 const float* __restrict__ G1, const float* __restrict__ G2,
                                                 __half* __restrict__ Bf, float* __restrict__ cvec) {
  int bb = blockIdx.x;
  const float* G = (bb < 385) ? G1 : G2;
  int off = (bb < 385) ? 0 : 256;
  int r = (bb < 385) ? bb : bb - 385;  // 0..384: K index (384 rows) + 1 bias row
  int j = threadIdx.x;                 // col within 256
  float acc = 0.f;
  if (r < 256) {
    for (int m = 0; m < 128; m++) acc += T1w[r * 128 + m] * G[m * 256 + j];
  } else if (r < 384) {
    int rr = r - 256;
    for (int m = 0; m < 128; m++) acc += T2w[rr * 128 + m] * G[(128 + m) * 256 + j];
  } else {
    for (int m = 0; m < 128; m++) acc += T1b[m] * G[m * 256 + j] + T2b[m] * G[(128 + m) * 256 + j];
    cvec[off + j] = acc;
    return;
  }
  int k = r, colabs = off + j;
  int kt = k >> 5, lq = (k >> 3) & 3, j8 = k & 7;
  int cb = colabs >> 7, colr = colabs & 127, ni = colr >> 4, lr = colr & 15;
  size_t idx = ((size_t)(((cb * 12 + kt) * 8 + ni) * 4 + lq) * 16 + lr) * 8 + j8;
  Bf[idx] = __float2half(acc);
}

// async global->LDS, 16B per lane; LDS dest is wave-uniform base + lane*16
#define GLL(GP, LP)                                                     \
  __builtin_amdgcn_global_load_lds(                                     \
      (const __attribute__((address_space(1))) void*)(GP),              \
      (__attribute__((address_space(3))) void*)(LP), 16, 0, 0)

// ---- fp16 MFMA GEMM: C[N,512] = [sm|sp][N,384] @ Wc[384,512] + cvec; outputs fp16 ----
// v5: single-term fp16 MFMA (error analysis: fused-weight magnitudes ~0.028 -> fp16 product
// error ~ the fp16 feature-store error already present). 1/3 the MFMA, 1/2 the LDS of
// split-bf16. Depth-2 rolling pipeline: 3 LDS slots (24 KB), raw s_barrier + counted vmcnt
// so stage st+2 staging stays in flight across barriers; A register-prefetched 1 stage.
// vmcnt invariant at stage end: outstanding = [G(st+1):2][A(st+1):4][G(st+2):2] -> vmcnt(6)
// retires exactly G(st+1) (oldest, in-order retirement), regardless of intra-stage reorder.
// ~60 VGPR + 64 acc <= 128/wave -> 4 blocks/CU.
__global__ __launch_bounds__(256, 4) void k_gemm(const float* __restrict__ sm, const float* __restrict__ sp,
                                                 const u16* __restrict__ Bf, const float* __restrict__ cvec,
                                                 __half* __restrict__ fs, __half* __restrict__ fd, int N) {
  __shared__ u16 BFl[3 * 4096];  // 3 slots x 8 KB: k-tile = 8 ni x 64 lanes x 8 halves
  int tid = threadIdx.x, w = tid >> 6, l = tid & 63;
  int lr = l & 15, lq = l >> 4;
  // bijective XCD-sibling swizzle: the 4 col-siblings of a row-panel share L%8 -> same XCD
  int L = blockIdx.x;
  int x = L & 7, m = L >> 3;
  int cb = m & 3;
  int rb = x + 8 * (m >> 2);
  int col0 = cb * 128, row0 = rb * 128;
  if (row0 >= N) return;  // padded row-panels: whole block exits uniformly (before barriers)
  int r0 = row0 + w * 32 + lr;
  int r1 = r0 + 16;
  int c0 = r0 < N ? r0 : N - 1;
  int c1 = r1 < N ? r1 : N - 1;
  const float* psm0 = sm + (size_t)c0 * 256 + lq * 8;
  const float* psm1 = sm + (size_t)c1 * 256 + lq * 8;
  const float* psp0 = sp + (size_t)c0 * 128 + lq * 8;
  const float* psp1 = sp + (size_t)c1 * 128 + lq * 8;

  f32x4 acc[2][8];
#pragma unroll
  for (int mt = 0; mt < 2; mt++)
#pragma unroll
    for (int ni = 0; ni < 8; ni++) acc[mt][ni] = (f32x4){0.f, 0.f, 0.f, 0.f};

  // stage B k-tile S into LDS slot BUF (identity map, wave-uniform LDS base); 2 GLL/thread
#define STAGE_B(S, BUF)                                                 \
  {                                                                     \
    size_t g0 = (size_t)(cb * 12 + (S)) * 4096;                         \
    _Pragma("unroll") for (int i = 0; i < 2; i++) {                     \
      int c = i * 256 + tid;                                            \
      int lb = (BUF)*4096 + (i * 4 + w) * 512;                          \
      GLL(Bf + g0 + (size_t)c * 8, &BFl[lb]);                           \
    }                                                                   \
  }

  // load A k-tile P (P in [0,12)) into D[0..3]: 2 rows x 8 floats
#define LOADA(P, D)                                                     \
  {                                                                     \
    const float* _g0 = ((P) < 8) ? (psm0 + (P)*32) : (psp0 + ((P)-8) * 32); \
    const float* _g1 = ((P) < 8) ? (psm1 + (P)*32) : (psp1 + ((P)-8) * 32); \
    D[0] = *(const float4*)_g0;                                         \
    D[1] = *(const float4*)(_g0 + 4);                                   \
    D[2] = *(const float4*)_g1;                                         \
    D[3] = *(const float4*)(_g1 + 4);                                   \
  }

  float4 Aa[4], Ab[4];  // stage-level ping-pong (statically selected under full unroll)
  LOADA(0, Aa);         // [A0:4]
  STAGE_B(0, 0);        // [G0:2]
  STAGE_B(1, 1);        // [G1:2]
  asm volatile("s_waitcnt vmcnt(2)" ::: "memory");  // retire A0+G0, keep G1 in flight
  __builtin_amdgcn_sched_barrier(0);
  __builtin_amdgcn_s_barrier();

#pragma unroll
  for (int st = 0; st < 12; st++) {
    const int slot = st % 3;
    const float4* Dc = (st & 1) ? Ab : Aa;
    float4* Dn = (st & 1) ? Aa : Ab;
    if (st < 11) LOADA(st + 1, Dn);              // A(st+1): in flight through this stage
    if (st < 10) STAGE_B(st + 2, (st + 2) % 3);  // G(st+2): in flight across next barrier
    // convert A(st) to fp16 fragments (compiler auto-waits the right vmcnt)
    f16x8 a0, a1;
    a0[0] = (_Float16)Dc[0].x; a0[1] = (_Float16)Dc[0].y;
    a0[2] = (_Float16)Dc[0].z; a0[3] = (_Float16)Dc[0].w;
    a0[4] = (_Float16)Dc[1].x; a0[5] = (_Float16)Dc[1].y;
    a0[6] = (_Float16)Dc[1].z; a0[7] = (_Float16)Dc[1].w;
    a1[0] = (_Float16)Dc[2].x; a1[1] = (_Float16)Dc[2].y;
    a1[2] = (_Float16)Dc[2].z; a1[3] = (_Float16)Dc[2].w;
    a1[4] = (_Float16)Dc[3].x; a1[5] = (_Float16)Dc[3].y;
    a1[6] = (_Float16)Dc[3].z; a1[7] = (_Float16)Dc[3].w;
#pragma unroll
    for (int ni = 0; ni < 8; ni++) {
      int lo = slot * 4096 + (ni * 64 + l) * 8;  // lane-contiguous: zero bank conflicts
      f16x8 bf = *(const f16x8*)&BFl[lo];
      acc[0][ni] = __builtin_amdgcn_mfma_f32_16x16x32_f16(a0, bf, acc[0][ni], 0, 0, 0);
      acc[1][ni] = __builtin_amdgcn_mfma_f32_16x16x32_f16(a1, bf, acc[1][ni], 0, 0, 0);
    }
    // retire G(st+1) before the barrier; keep A(st+1) + G(st+2) in flight
    if (st < 10) {
      asm volatile("s_waitcnt vmcnt(6)" ::: "memory");
    } else if (st == 10) {
      asm volatile("s_waitcnt vmcnt(4)" ::: "memory");  // no G(12); keep A(11) only
    }
    if (st < 11) {
      __builtin_amdgcn_sched_barrier(0);
      __builtin_amdgcn_s_barrier();
    }
  }

  // epilogue: C row = lq*4 + reg, col = lane&15 per 16x16 tile; store fp16
#pragma unroll
  for (int mt = 0; mt < 2; mt++) {
    int rbr = row0 + w * 32 + mt * 16 + lq * 4;
#pragma unroll
    for (int ni = 0; ni < 8; ni++) {
      int c = col0 + ni * 16 + lr;
      float cv = cvec[c];
      __half* op = fs; int cc = c;
      if (c >= 256) { op = fd; cc = c - 256; }
#pragma unroll
      for (int r = 0; r < 4; r++) {
        int rr = rbr + r;
        if (rr < N) op[(size_t)rr * 256 + cc] = __float2half(acc[mt][ni][r] + cv);
      }
    }
  }
#undef STAGE_B
#undef LOADA
}

// ---- layer-2 feature GEMM: fs/fd[N,256] = h[N,32] @ W[32,256] ----
__global__ __launch_bounds__(256) void k_feat2(const float* __restrict__ h, const float* __restrict__ Ws,
                                               const float* __restrict__ Wd, __half* __restrict__ fs,
                                               __half* __restrict__ fd, int N) {
  int j = threadIdx.x;
  int n0 = blockIdx.x * 32;
  float ws[32], wd[32];
#pragma unroll
  for (int k = 0; k < 32; k++) {
    ws[k] = Ws[k * 256 + j];
    wd[k] = Wd[k * 256 + j];
  }
  int nend = n0 + 32; if (nend > N) nend = N;
#pragma unroll 2
  for (int n = n0; n < nend; n++) {
    const float* hr = h + (size_t)n * 32;  // wave-uniform -> scalar loads
    float as = 0.f, ad = 0.f;
#pragma unroll
    for (int k = 0; k < 32; k++) {
      float hv = hr[k];
      as += hv * ws[k];
      ad += hv * wd[k];
    }
    fs[(size_t)n * 256 + j] = __float2half(as);
    fd[(size_t)n * 256 + j] = __float2half(ad);
  }
}

// ---- fused edge pass, packed-fp16 math: per-dst softmax + aggregate + bias (+elu) + head-mean ----
// 4-edge ILP with one-quad software pipeline; one wave per dst node; lane L holds elems 4L..4L+3
template <int FINAL>
__global__ __launch_bounds__(256) void k_edge(const uint2* __restrict__ fs, const uint2* __restrict__ fd,
                                              const int* __restrict__ csr_src, const int* __restrict__ rp,
                                              const float* __restrict__ attn, const float* __restrict__ bias,
                                              float* __restrict__ out, int N) {
  int n = blockIdx.x * 4 + (threadIdx.x >> 6);
  if (n >= N) return;
  int lane = threadIdx.x & 63;
  float4 av = ((const float4*)attn)[lane];
  H2 AV01, AV23, Y01, Y23;
  AV01.v = (f16x2){(_Float16)av.x, (_Float16)av.y};
  AV23.v = (f16x2){(_Float16)av.z, (_Float16)av.w};
  const f16x2 c02 = {(_Float16)0.2f, (_Float16)0.2f};
  uint2 yu = fd[(size_t)n * 64 + lane];
  Y01.u = yu.x; Y23.u = yu.y;
  int beg = rp[n], end = rp[n + 1];
  float den0 = 0.f, den1 = 0.f;
  float4 acc0 = {0.f, 0.f, 0.f, 0.f}, acc1 = {0.f, 0.f, 0.f, 0.f};

  auto edge1 = [&](uint2 xu, float& den, float4& acc) {
    H2 Xa, Xb; Xa.u = xu.x; Xb.u = xu.y;
    f16x2 ea = Xa.v + Y01.v, eb = Xb.v + Y23.v;
    f16x2 ta = __builtin_elementwise_max(ea, ea * c02);
    f16x2 tb = __builtin_elementwise_max(eb, eb * c02);
    float p = __builtin_amdgcn_fdot2(ta, AV01.v, 0.f, false);
    p = __builtin_amdgcn_fdot2(tb, AV23.v, p, false);
    p += __shfl_xor(p, 1, 64);
    p += __shfl_xor(p, 2, 64);
    p += __shfl_xor(p, 4, 64);
    float wgt = __expf(p);  // scores bounded: exp-safe without max shift
    den += wgt;
    acc.x += wgt * (float)Xa.v.x; acc.y += wgt * (float)Xa.v.y;
    acc.z += wgt * (float)Xb.v.x; acc.w += wgt * (float)Xb.v.y;
  };

  int e = beg;
  int nq = (end - beg) >> 2;
  if (nq > 0) {
    int s0 = csr_src[e], s1 = csr_src[e + 1], s2 = csr_src[e + 2], s3 = csr_src[e + 3];
    uint2 x0 = fs[(size_t)s0 * 64 + lane];
    uint2 x1 = fs[(size_t)s1 * 64 + lane];
    uint2 x2 = fs[(size_t)s2 * 64 + lane];
    uint2 x3 = fs[(size_t)s3 * 64 + lane];
    for (int q = 1; q < nq; q++) {
      int b2 = e + 4 * q;  // next quad (always in-bounds: q < nq)
      int t0 = csr_src[b2], t1 = csr_src[b2 + 1], t2 = csr_src[b2 + 2], t3 = csr_src[b2 + 3];
      uint2 y0 = fs[(size_t)t0 * 64 + lane];
      uint2 y1 = fs[(size_t)t1 * 64 + lane];
      uint2 y2 = fs[(size_t)t2 * 64 + lane];
      uint2 y3 = fs[(size_t)t3 * 64 + lane];
      edge1(x0, den0, acc0); edge1(x1, den1, acc1);
      edge1(x2, den0, acc0); edge1(x3, den1, acc1);
      x0 = y0; x1 = y1; x2 = y2; x3 = y3;
    }
    edge1(x0, den0, acc0); edge1(x1, den1, acc1);
    edge1(x2, den0, acc0); edge1(x3, den1, acc1);
    e += 4 * nq;
  }
  for (; e < end; e++) {
    int s0 = csr_src[e];
    uint2 xu = fs[(size_t)s0 * 64 + lane];
    edge1(xu, den0, acc0);
  }

  float4 acc = {acc0.x + acc1.x, acc0.y + acc1.y, acc0.z + acc1.z, acc0.w + acc1.w};
  float invd = 1.f / (den0 + den1);
  float4 b = ((const float4*)bias)[lane];
  acc.x = acc.x * invd + b.x;
  acc.y = acc.y * invd + b.y;
  acc.z = acc.z * invd + b.z;
  acc.w = acc.w * invd + b.w;
  if (!FINAL) {
    acc.x = acc.x > 0.f ? acc.x : expm1f(acc.x);
    acc.y = acc.y > 0.f ? acc.y : expm1f(acc.y);
    acc.z = acc.z > 0.f ? acc.z : expm1f(acc.z);
    acc.w = acc.w > 0.f ? acc.w : expm1f(acc.w);
  }
#pragma unroll
  for (int mask = 8; mask <= 32; mask <<= 1) {
    acc.x += __shfl_xor(acc.x, mask, 64);
    acc.y += __shfl_xor(acc.y, mask, 64);
    acc.z += __shfl_xor(acc.z, mask, 64);
    acc.w += __shfl_xor(acc.w, mask, 64);
  }
  if (lane < 8) {
    float4 o = {acc.x * 0.125f, acc.y * 0.125f, acc.z * 0.125f, acc.w * 0.125f};
    ((float4*)out)[(size_t)n * 8 + lane] = o;
  }
}

extern "C" void kernel_launch(void* const* d_in, const int* in_sizes, int n_in,
                              void* d_out, int out_size, void* d_ws, size_t ws_size,
                              hipStream_t stream) {
  const float* sm  = (const float*)d_in[0];
  const float* sp  = (const float*)d_in[1];
  const int*   src = (const int*)d_in[2];
  const int*   dst = (const int*)d_in[3];
  const float* T1w = (const float*)d_in[4];
  const float* T1b = (const float*)d_in[5];
  const float* T2w = (const float*)d_in[6];
  const float* T2b = (const float*)d_in[7];
  const float* g1sw = (const float*)d_in[8];
  const float* g1dw = (const float*)d_in[9];
  const float* g1a  = (const float*)d_in[10];
  const float* g1b  = (const float*)d_in[11];
  const float* g2sw = (const float*)d_in[12];
  const float* g2dw = (const float*)d_in[13];
  const float* g2a  = (const float*)d_in[14];
  const float* g2b  = (const float*)d_in[15];
  const int N = in_sizes[1] / 128;  // sp_feats is [N,128]
  const int E = in_sizes[2];
  float* out = (float*)d_out;

  size_t off = 0;
  char* wsb = (char*)d_ws;
  auto alloc = [&](size_t bytes) -> void* {
    void* p = wsb + off;
    off += (bytes + 255) & ~(size_t)255;
    return p;
  };
  __half* Bf  = (__half*)alloc((size_t)512 * 384 * 2);
  float* cvec  = (float*)alloc(512 * 4);
  int* deg     = (int*)alloc((size_t)N * 4);
  int* cnt     = (int*)alloc((size_t)N * 4);
  int* row_ptr = (int*)alloc((size_t)(N + 1) * 4);
  int* blksum  = (int*)alloc(4096 * 4);
  int* csr_src = (int*)alloc((size_t)E * 4);
  __half* fs   = (__half*)alloc((size_t)N * 256 * 2);
  __half* fd   = (__half*)alloc((size_t)N * 256 * 2);
  float* hmid  = (float*)alloc((size_t)N * 32 * 4);
  (void)ws_size; (void)n_in; (void)out_size;

  (void)hipMemsetAsync(deg, 0, (size_t)N * 4, stream);
  (void)hipMemsetAsync(cnt, 0, (size_t)N * 4, stream);

  // CSR by destination (shared by both layers)
  k_deg<<<(E + 255) / 256, 256, 0, stream>>>(dst, deg, E);
  int nblk = (N + 1023) / 1024;
  k_blkscan<<<nblk, 256, 0, stream>>>(deg, row_ptr, blksum, N);
  k_scan_top<<<1, 64, 0, stream>>>(blksum, nblk);
  k_addoff<<<(N + 255) / 256, 256, 0, stream>>>(row_ptr, blksum, N, E);
  k_fill<<<(E + 255) / 256, 256, 0, stream>>>(src, dst, row_ptr, cnt, csr_src, E);

  // fold T1/T2 into layer-1 weights, fp16, fragment-ordered (both halves, one launch)
  k_precomb<<<770, 256, 0, stream>>>(T1w, T1b, T2w, T2b, g1sw, g1dw, Bf, cvec);

  // layer 1: 128-row panels x 4 col-blocks, XCD-swizzled; panels padded to a multiple of 8
  int rbs = (N + 127) / 128;
  int rbp = (rbs + 7) & ~7;
  k_gemm<<<dim3(rbp * 4), 256, 0, stream>>>(sm, sp, (const u16*)Bf, cvec, fs, fd, N);
  k_edge<0><<<(N + 3) / 4, 256, 0, stream>>>((const uint2*)fs, (const uint2*)fd, csr_src, row_ptr, g1a, g1b, hmid, N);

  // layer 2
  k_feat2<<<(N + 31) / 32, 256, 0, stream>>>(hmid, g2sw, g2dw, fs, fd, N);
  k_edge<1><<<(N + 3) / 4, 256, 0, stream>>>((const uint2*)fs, (const uint2*)fd, csr_src, row_ptr, g2a, g2b, out, N);
}

// Round 6
// 456.457 us; speedup vs baseline: 1.1336x; 1.0122x over previous
//
#include <hip/hip_runtime.h>
#include <hip/hip_fp16.h>

// N=50000 nodes, E=850000 edges, H=8 heads, D=32, H*D=256, IN=128, SM=256, SP=128

typedef unsigned int uint32;
typedef unsigned short u16;
typedef float f32x4 __attribute__((ext_vector_type(4)));
typedef _Float16 f16x2 __attribute__((ext_vector_type(2)));
typedef _Float16 f16x8 __attribute__((ext_vector_type(8)));

union H2 { f16x2 v; uint32 u; };

__device__ __forceinline__ int wave_incl_scan(int x) {
  int lane = threadIdx.x & 63;
#pragma unroll
  for (int off = 1; off < 64; off <<= 1) {
    int t = __shfl_up(x, off, 64);
    if (lane >= off) x += t;
  }
  return x;
}

// ---------------- CSR build ----------------
__global__ __launch_bounds__(256) void k_deg(const int* __restrict__ dst, int* __restrict__ deg, int E) {
  int e = blockIdx.x * 256 + threadIdx.x;
  if (e < E) atomicAdd(&deg[dst[e]], 1);
}

__global__ __launch_bounds__(256) void k_blkscan(const int* __restrict__ in, int* __restrict__ out,
                                                 int* __restrict__ blksum, int n) {
  __shared__ int wsum[4];
  int tid = threadIdx.x;
  int i0 = blockIdx.x * 1024 + tid * 4;
  int v0 = 0, v1 = 0, v2 = 0, v3 = 0;
  if (i0 + 3 < n) {
    int4 t = *(const int4*)(in + i0);
    v0 = t.x; v1 = t.y; v2 = t.z; v3 = t.w;
  } else {
    if (i0 < n) v0 = in[i0];
    if (i0 + 1 < n) v1 = in[i0 + 1];
    if (i0 + 2 < n) v2 = in[i0 + 2];
    if (i0 + 3 < n) v3 = in[i0 + 3];
  }
  int ts = v0 + v1 + v2 + v3;
  int incl = wave_incl_scan(ts);
  int lane = tid & 63, wid = tid >> 6;
  if (lane == 63) wsum[wid] = incl;
  __syncthreads();
  if (tid == 0) {
    int a = wsum[0], b = wsum[1], c = wsum[2], d = wsum[3];
    wsum[0] = 0; wsum[1] = a; wsum[2] = a + b; wsum[3] = a + b + c;
    blksum[blockIdx.x] = a + b + c + d;
  }
  __syncthreads();
  int excl = wsum[wid] + incl - ts;
  if (i0 + 3 < n) {
    int4 o; o.x = excl; o.y = excl + v0; o.z = excl + v0 + v1; o.w = excl + v0 + v1 + v2;
    *(int4*)(out + i0) = o;
  } else {
    if (i0 < n) out[i0] = excl;
    if (i0 + 1 < n) out[i0 + 1] = excl + v0;
    if (i0 + 2 < n) out[i0 + 2] = excl + v0 + v1;
    if (i0 + 3 < n) out[i0 + 3] = excl + v0 + v1 + v2;
  }
}

__global__ void k_scan_top(int* __restrict__ bs, int G) {
  int lane = threadIdx.x;  // 64 threads
  int base = 0;
  for (int s = 0; s < G; s += 64) {
    int i = s + lane;
    int v = (i < G) ? bs[i] : 0;
    int incl = wave_incl_scan(v);
    if (i < G) bs[i] = base + incl - v;
    base += __shfl(incl, 63, 64);
  }
}

__global__ __launch_bounds__(256) void k_addoff(int* __restrict__ rp, const int* __restrict__ bs, int n, int Etot) {
  int i = blockIdx.x * 256 + threadIdx.x;
  if (i < n) rp[i] += bs[i >> 10];
  if (i == 0) rp[n] = Etot;
}

__global__ __launch_bounds__(256) void k_fill(const int* __restrict__ src, const int* __restrict__ dst,
                                              const int* __restrict__ rp, int* __restrict__ cnt,
                                              int* __restrict__ csr_src, int E) {
  int e = blockIdx.x * 256 + threadIdx.x;
  if (e < E) {
    int d = dst[e];
    int p = rp[d] + atomicAdd(&cnt[d], 1);
    csr_src[p] = src[e];
  }
}

// ---- combined layer-1 weights, fp16, stored in MFMA-fragment order ----
// Bfrag index: ((((cb*12 + kt)*8 + ni)*4 + lq)*16 + lr)*8 + j8
// Merged launch: blocks [0,385) -> G1 (off 0), [385,770) -> G2 (off 256)
__global__ __launch_bounds__(256) void k_precomb(const float* __restrict__ T1w, const float* __restrict__ T1b,
                                                 const float* __restrict__ T2w, const float* __restrict__ T2b,
                                                 const float* __restrict__ G1, const float* __restrict__ G2,
                                                 __half* __restrict__ Bf, float* __restrict__ cvec) {
  int bb = blockIdx.x;
  const float* G = (bb < 385) ? G1 : G2;
  int off = (bb < 385) ? 0 : 256;
  int r = (bb < 385) ? bb : bb - 385;  // 0..384: K index (384 rows) + 1 bias row
  int j = threadIdx.x;                 // col within 256
  float acc = 0.f;
  if (r < 256) {
    for (int m = 0; m < 128; m++) acc += T1w[r * 128 + m] * G[m * 256 + j];
  } else if (r < 384) {
    int rr = r - 256;
    for (int m = 0; m < 128; m++) acc += T2w[rr * 128 + m] * G[(128 + m) * 256 + j];
  } else {
    for (int m = 0; m < 128; m++) acc += T1b[m] * G[m * 256 + j] + T2b[m] * G[(128 + m) * 256 + j];
    cvec[off + j] = acc;
    return;
  }
  int k = r, colabs = off + j;
  int kt = k >> 5, lq = (k >> 3) & 3, j8 = k & 7;
  int cb = colabs >> 7, colr = colabs & 127, ni = colr >> 4, lr = colr & 15;
  size_t idx = ((size_t)(((cb * 12 + kt) * 8 + ni) * 4 + lq) * 16 + lr) * 8 + j8;
  Bf[idx] = __float2half(acc);
}

// async global->LDS, 16B per lane; LDS dest is wave-uniform base + lane*16
#define GLL(GP, LP)                                                     \
  __builtin_amdgcn_global_load_lds(                                     \
      (const __attribute__((address_space(1))) void*)(GP),              \
      (__attribute__((address_space(3))) void*)(LP), 16, 0, 0)

// ---- fp16 MFMA GEMM: C[N,512] = [sm|sp][N,384] @ Wc[384,512] + cvec; outputs fp16 ----
// v5 (proven): single-term fp16 MFMA, depth-2 rolling pipeline, 3 LDS slots, raw s_barrier
// + counted vmcnt; A register-prefetched one stage; XCD-sibling swizzle; 4 blocks/CU.
__global__ __launch_bounds__(256, 4) void k_gemm(const float* __restrict__ sm, const float* __restrict__ sp,
                                                 const u16* __restrict__ Bf, const float* __restrict__ cvec,
                                                 __half* __restrict__ fs, __half* __restrict__ fd, int N) {
  __shared__ u16 BFl[3 * 4096];  // 3 slots x 8 KB: k-tile = 8 ni x 64 lanes x 8 halves
  int tid = threadIdx.x, w = tid >> 6, l = tid & 63;
  int lr = l & 15, lq = l >> 4;
  int L = blockIdx.x;
  int x = L & 7, m = L >> 3;
  int cb = m & 3;
  int rb = x + 8 * (m >> 2);
  int col0 = cb * 128, row0 = rb * 128;
  if (row0 >= N) return;  // padded row-panels: whole block exits uniformly (before barriers)
  int r0 = row0 + w * 32 + lr;
  int r1 = r0 + 16;
  int c0 = r0 < N ? r0 : N - 1;
  int c1 = r1 < N ? r1 : N - 1;
  const float* psm0 = sm + (size_t)c0 * 256 + lq * 8;
  const float* psm1 = sm + (size_t)c1 * 256 + lq * 8;
  const float* psp0 = sp + (size_t)c0 * 128 + lq * 8;
  const float* psp1 = sp + (size_t)c1 * 128 + lq * 8;

  f32x4 acc[2][8];
#pragma unroll
  for (int mt = 0; mt < 2; mt++)
#pragma unroll
    for (int ni = 0; ni < 8; ni++) acc[mt][ni] = (f32x4){0.f, 0.f, 0.f, 0.f};

#define STAGE_B(S, BUF)                                                 \
  {                                                                     \
    size_t g0 = (size_t)(cb * 12 + (S)) * 4096;                         \
    _Pragma("unroll") for (int i = 0; i < 2; i++) {                     \
      int c = i * 256 + tid;                                            \
      int lb = (BUF)*4096 + (i * 4 + w) * 512;                          \
      GLL(Bf + g0 + (size_t)c * 8, &BFl[lb]);                           \
    }                                                                   \
  }

#define LOADA(P, D)                                                     \
  {                                                                     \
    const float* _g0 = ((P) < 8) ? (psm0 + (P)*32) : (psp0 + ((P)-8) * 32); \
    const float* _g1 = ((P) < 8) ? (psm1 + (P)*32) : (psp1 + ((P)-8) * 32); \
    D[0] = *(const float4*)_g0;                                         \
    D[1] = *(const float4*)(_g0 + 4);                                   \
    D[2] = *(const float4*)_g1;                                         \
    D[3] = *(const float4*)(_g1 + 4);                                   \
  }

  float4 Aa[4], Ab[4];  // stage-level ping-pong (statically selected under full unroll)
  LOADA(0, Aa);         // [A0:4]
  STAGE_B(0, 0);        // [G0:2]
  STAGE_B(1, 1);        // [G1:2]
  asm volatile("s_waitcnt vmcnt(2)" ::: "memory");  // retire A0+G0, keep G1 in flight
  __builtin_amdgcn_sched_barrier(0);
  __builtin_amdgcn_s_barrier();

#pragma unroll
  for (int st = 0; st < 12; st++) {
    const int slot = st % 3;
    const float4* Dc = (st & 1) ? Ab : Aa;
    float4* Dn = (st & 1) ? Aa : Ab;
    if (st < 11) LOADA(st + 1, Dn);              // A(st+1): in flight through this stage
    if (st < 10) STAGE_B(st + 2, (st + 2) % 3);  // G(st+2): in flight across next barrier
    f16x8 a0, a1;
    a0[0] = (_Float16)Dc[0].x; a0[1] = (_Float16)Dc[0].y;
    a0[2] = (_Float16)Dc[0].z; a0[3] = (_Float16)Dc[0].w;
    a0[4] = (_Float16)Dc[1].x; a0[5] = (_Float16)Dc[1].y;
    a0[6] = (_Float16)Dc[1].z; a0[7] = (_Float16)Dc[1].w;
    a1[0] = (_Float16)Dc[2].x; a1[1] = (_Float16)Dc[2].y;
    a1[2] = (_Float16)Dc[2].z; a1[3] = (_Float16)Dc[2].w;
    a1[4] = (_Float16)Dc[3].x; a1[5] = (_Float16)Dc[3].y;
    a1[6] = (_Float16)Dc[3].z; a1[7] = (_Float16)Dc[3].w;
#pragma unroll
    for (int ni = 0; ni < 8; ni++) {
      int lo = slot * 4096 + (ni * 64 + l) * 8;  // lane-contiguous: zero bank conflicts
      f16x8 bf = *(const f16x8*)&BFl[lo];
      acc[0][ni] = __builtin_amdgcn_mfma_f32_16x16x32_f16(a0, bf, acc[0][ni], 0, 0, 0);
      acc[1][ni] = __builtin_amdgcn_mfma_f32_16x16x32_f16(a1, bf, acc[1][ni], 0, 0, 0);
    }
    if (st < 10) {
      asm volatile("s_waitcnt vmcnt(6)" ::: "memory");
    } else if (st == 10) {
      asm volatile("s_waitcnt vmcnt(4)" ::: "memory");  // no G(12); keep A(11) only
    }
    if (st < 11) {
      __builtin_amdgcn_sched_barrier(0);
      __builtin_amdgcn_s_barrier();
    }
  }

  // epilogue: C row = lq*4 + reg, col = lane&15 per 16x16 tile; store fp16
#pragma unroll
  for (int mt = 0; mt < 2; mt++) {
    int rbr = row0 + w * 32 + mt * 16 + lq * 4;
#pragma unroll
    for (int ni = 0; ni < 8; ni++) {
      int c = col0 + ni * 16 + lr;
      float cv = cvec[c];
      __half* op = fs; int cc = c;
      if (c >= 256) { op = fd; cc = c - 256; }
#pragma unroll
      for (int r = 0; r < 4; r++) {
        int rr = rbr + r;
        if (rr < N) op[(size_t)rr * 256 + cc] = __float2half(acc[mt][ni][r] + cv);
      }
    }
  }
#undef STAGE_B
#undef LOADA
}

// ---- layer-2 feature GEMM: fs/fd[N,256] = h[N,32] @ W[32,256] ----
__global__ __launch_bounds__(256) void k_feat2(const float* __restrict__ h, const float* __restrict__ Ws,
                                               const float* __restrict__ Wd, __half* __restrict__ fs,
                                               __half* __restrict__ fd, int N) {
  int j = threadIdx.x;
  int n0 = blockIdx.x * 32;
  float ws[32], wd[32];
#pragma unroll
  for (int k = 0; k < 32; k++) {
    ws[k] = Ws[k * 256 + j];
    wd[k] = Wd[k * 256 + j];
  }
  int nend = n0 + 32; if (nend > N) nend = N;
#pragma unroll 2
  for (int n = n0; n < nend; n++) {
    const float* hr = h + (size_t)n * 32;  // wave-uniform -> scalar loads
    float as = 0.f, ad = 0.f;
#pragma unroll
    for (int k = 0; k < 32; k++) {
      float hv = hr[k];
      as += hv * ws[k];
      ad += hv * wd[k];
    }
    fs[(size_t)n * 256 + j] = __float2half(as);
    fd[(size_t)n * 256 + j] = __float2half(ad);
  }
}

// ---- fused edge pass v6: HALF-WAVE EDGE PAIRING ----
// Lane reads uint4 (8 feats); 32 lanes cover a 512B row; the two wave halves process TWO
// edges at once -> every inner-loop instruction serves 2 edges, softmax reduce is 2 shfl
// (4-lane head groups), one dwordx4 gather per pair. Tail edge: half-B weight forced to 0.
// Epilogue: cross-half combine (xor 32), bias (+elu), head-mean via xor {4,8,16}.
template <int FINAL>
__global__ __launch_bounds__(256) void k_edge(const uint4* __restrict__ fs4, const uint4* __restrict__ fd4,
                                              const int* __restrict__ csr_src, const int* __restrict__ rp,
                                              const float* __restrict__ attn, const float* __restrict__ bias,
                                              float* __restrict__ out, int N) {
  int n = blockIdx.x * 4 + (threadIdx.x >> 6);
  if (n >= N) return;
  int lane = threadIdx.x & 63;
  int lh = lane & 31;  // position within half; lane holds feats 8*lh .. 8*lh+7
  float4 a0 = ((const float4*)attn)[lh * 2];
  float4 a1 = ((const float4*)attn)[lh * 2 + 1];
  H2 AV01, AV23, AV45, AV67;
  AV01.v = (f16x2){(_Float16)a0.x, (_Float16)a0.y};
  AV23.v = (f16x2){(_Float16)a0.z, (_Float16)a0.w};
  AV45.v = (f16x2){(_Float16)a1.x, (_Float16)a1.y};
  AV67.v = (f16x2){(_Float16)a1.z, (_Float16)a1.w};
  const f16x2 c02 = {(_Float16)0.2f, (_Float16)0.2f};
  uint4 yu = fd4[(size_t)n * 32 + lh];
  H2 Y01, Y23, Y45, Y67;
  Y01.u = yu.x; Y23.u = yu.y; Y45.u = yu.z; Y67.u = yu.w;
  int beg = rp[n], end = rp[n + 1];
  float den = 0.f;
  float acc[8] = {0.f, 0.f, 0.f, 0.f, 0.f, 0.f, 0.f, 0.f};

  auto pair1 = [&](uint4 xu, bool tail) {
    H2 Xa, Xb, Xc, Xd;
    Xa.u = xu.x; Xb.u = xu.y; Xc.u = xu.z; Xd.u = xu.w;
    f16x2 e0 = Xa.v + Y01.v, e1 = Xb.v + Y23.v, e2 = Xc.v + Y45.v, e3 = Xd.v + Y67.v;
    f16x2 t0 = __builtin_elementwise_max(e0, e0 * c02);
    f16x2 t1 = __builtin_elementwise_max(e1, e1 * c02);
    f16x2 t2 = __builtin_elementwise_max(e2, e2 * c02);
    f16x2 t3 = __builtin_elementwise_max(e3, e3 * c02);
    float p = __builtin_amdgcn_fdot2(t0, AV01.v, 0.f, false);
    p = __builtin_amdgcn_fdot2(t1, AV23.v, p, false);
    p = __builtin_amdgcn_fdot2(t2, AV45.v, p, false);
    p = __builtin_amdgcn_fdot2(t3, AV67.v, p, false);
    p += __shfl_xor(p, 1, 64);  // 4-lane head group reduce
    p += __shfl_xor(p, 2, 64);
    float wgt = __expf(p);  // scores bounded: exp-safe without max shift
    if (tail && lane >= 32) wgt = 0.f;  // odd-degree tail: half B invalid
    den += wgt;
    acc[0] += wgt * (float)Xa.v.x; acc[1] += wgt * (float)Xa.v.y;
    acc[2] += wgt * (float)Xb.v.x; acc[3] += wgt * (float)Xb.v.y;
    acc[4] += wgt * (float)Xc.v.x; acc[5] += wgt * (float)Xc.v.y;
    acc[6] += wgt * (float)Xd.v.x; acc[7] += wgt * (float)Xd.v.y;
  };

  int e = beg;
  int np = (end - beg) >> 1;
  if (np > 0) {
    int sA = csr_src[e], sB = csr_src[e + 1];  // wave-uniform scalar loads
    int s = (lane < 32) ? sA : sB;
    uint4 xcur = fs4[(size_t)s * 32 + lh];
    for (int q = 1; q < np; q++) {
      int eb = e + 2 * q;
      int tA = csr_src[eb], tB = csr_src[eb + 1];
      int t = (lane < 32) ? tA : tB;
      uint4 xnext = fs4[(size_t)t * 32 + lh];  // prefetch next pair
      pair1(xcur, false);
      xcur = xnext;
    }
    pair1(xcur, false);
    e += 2 * np;
  }
  if (e < end) {  // odd-degree tail
    int sA = csr_src[e];
    uint4 xu = fs4[(size_t)sA * 32 + lh];
    pair1(xu, true);
  }

  // cross-half combine: halves A/B accumulated disjoint edge subsets of the same dst
  den += __shfl_xor(den, 32, 64);
#pragma unroll
  for (int j = 0; j < 8; j++) acc[j] += __shfl_xor(acc[j], 32, 64);
  float invd = 1.f / den;
  float4 b0 = ((const float4*)bias)[lh * 2];
  float4 b1 = ((const float4*)bias)[lh * 2 + 1];
  float bj[8] = {b0.x, b0.y, b0.z, b0.w, b1.x, b1.y, b1.z, b1.w};
#pragma unroll
  for (int j = 0; j < 8; j++) {
    float v = acc[j] * invd + bj[j];
    if (!FINAL) v = v > 0.f ? v : expm1f(v);
    acc[j] = v;
  }
  // head-mean: feat f = lh*8+j; head h = lh>>2; d = (lh&3)*8+j -> reduce lanes stride-4
#pragma unroll
  for (int mask = 4; mask <= 16; mask <<= 1)
#pragma unroll
    for (int j = 0; j < 8; j++) acc[j] += __shfl_xor(acc[j], mask, 64);
  if (lane < 4) {  // lane p holds d = p*8 .. p*8+7
    float4 o0 = {acc[0] * 0.125f, acc[1] * 0.125f, acc[2] * 0.125f, acc[3] * 0.125f};
    float4 o1 = {acc[4] * 0.125f, acc[5] * 0.125f, acc[6] * 0.125f, acc[7] * 0.125f};
    ((float4*)out)[(size_t)n * 8 + lane * 2] = o0;
    ((float4*)out)[(size_t)n * 8 + lane * 2 + 1] = o1;
  }
}

extern "C" void kernel_launch(void* const* d_in, const int* in_sizes, int n_in,
                              void* d_out, int out_size, void* d_ws, size_t ws_size,
                              hipStream_t stream) {
  const float* sm  = (const float*)d_in[0];
  const float* sp  = (const float*)d_in[1];
  const int*   src = (const int*)d_in[2];
  const int*   dst = (const int*)d_in[3];
  const float* T1w = (const float*)d_in[4];
  const float* T1b = (const float*)d_in[5];
  const float* T2w = (const float*)d_in[6];
  const float* T2b = (const float*)d_in[7];
  const float* g1sw = (const float*)d_in[8];
  const float* g1dw = (const float*)d_in[9];
  const float* g1a  = (const float*)d_in[10];
  const float* g1b  = (const float*)d_in[11];
  const float* g2sw = (const float*)d_in[12];
  const float* g2dw = (const float*)d_in[13];
  const float* g2a  = (const float*)d_in[14];
  const float* g2b  = (const float*)d_in[15];
  const int N = in_sizes[1] / 128;  // sp_feats is [N,128]
  const int E = in_sizes[2];
  float* out = (float*)d_out;

  size_t off = 0;
  char* wsb = (char*)d_ws;
  auto alloc = [&](size_t bytes) -> void* {
    void* p = wsb + off;
    off += (bytes + 255) & ~(size_t)255;
    return p;
  };
  __half* Bf  = (__half*)alloc((size_t)512 * 384 * 2);
  float* cvec  = (float*)alloc(512 * 4);
  int* deg     = (int*)alloc((size_t)N * 4);
  int* cnt     = (int*)alloc((size_t)N * 4);
  int* row_ptr = (int*)alloc((size_t)(N + 1) * 4);
  int* blksum  = (int*)alloc(4096 * 4);
  int* csr_src = (int*)alloc((size_t)E * 4);
  __half* fs   = (__half*)alloc((size_t)N * 256 * 2);
  __half* fd   = (__half*)alloc((size_t)N * 256 * 2);
  float* hmid  = (float*)alloc((size_t)N * 32 * 4);
  (void)ws_size; (void)n_in; (void)out_size;

  (void)hipMemsetAsync(deg, 0, (size_t)N * 4, stream);
  (void)hipMemsetAsync(cnt, 0, (size_t)N * 4, stream);

  // CSR by destination (shared by both layers)
  k_deg<<<(E + 255) / 256, 256, 0, stream>>>(dst, deg, E);
  int nblk = (N + 1023) / 1024;
  k_blkscan<<<nblk, 256, 0, stream>>>(deg, row_ptr, blksum, N);
  k_scan_top<<<1, 64, 0, stream>>>(blksum, nblk);
  k_addoff<<<(N + 255) / 256, 256, 0, stream>>>(row_ptr, blksum, N, E);
  k_fill<<<(E + 255) / 256, 256, 0, stream>>>(src, dst, row_ptr, cnt, csr_src, E);

  // fold T1/T2 into layer-1 weights, fp16, fragment-ordered (both halves, one launch)
  k_precomb<<<770, 256, 0, stream>>>(T1w, T1b, T2w, T2b, g1sw, g1dw, Bf, cvec);

  // layer 1: 128-row panels x 4 col-blocks, XCD-swizzled; panels padded to a multiple of 8
  int rbs = (N + 127) / 128;
  int rbp = (rbs + 7) & ~7;
  k_gemm<<<dim3(rbp * 4), 256, 0, stream>>>(sm, sp, (const u16*)Bf, cvec, fs, fd, N);
  k_edge<0><<<(N + 3) / 4, 256, 0, stream>>>((const uint4*)fs, (const uint4*)fd, csr_src, row_ptr, g1a, g1b, hmid, N);

  // layer 2
  k_feat2<<<(N + 31) / 32, 256, 0, stream>>>(hmid, g2sw, g2dw, fs, fd, N);
  k_edge<1><<<(N + 3) / 4, 256, 0, stream>>>((const uint4*)fs, (const uint4*)fd, csr_src, row_ptr, g2a, g2b, out, N);
}